// Round 18
// baseline (284.376 us; speedup 1.0000x reference)
//
#include <hip/hip_runtime.h>

typedef unsigned short ushort_t;
typedef __attribute__((ext_vector_type(8))) short bf16x8;
typedef __attribute__((ext_vector_type(4))) float f32x4;
typedef __attribute__((ext_vector_type(16))) float f32x16;
typedef __attribute__((ext_vector_type(2))) __bf16 bf16v2;

#define BN 4
#define SEQ 2048
#define DIM 1024
#define NH 16
#define HDIM 64
#define MROWS (BN*SEQ)   // 8192
#define QSCALE 0.18033688011112042f   // 0.125 * log2(e): folded into Q so p = exp2(s)

__device__ __forceinline__ float bf2f(ushort_t s){ return __uint_as_float(((unsigned)s) << 16); }
__device__ __forceinline__ ushort_t f2bf(float f){
  unsigned u = __float_as_uint(f);
  u += 0x7fffu + ((u >> 16) & 1u);   // round-to-nearest-even
  return (ushort_t)(u >> 16);
}
__device__ __forceinline__ unsigned pack2(float a, float b){
  return (unsigned)f2bf(a) | ((unsigned)f2bf(b) << 16);
}

// async global->LDS copy, 16B per lane; LDS dest = wave-uniform base + lane*16
#define GLL16(gp, lp) __builtin_amdgcn_global_load_lds( \
    (const __attribute__((address_space(1))) void*)(gp), \
    (__attribute__((address_space(3))) void*)(lp), 16, 0, 0)

// ------- fused LN + w_qkv transpose in ONE dispatch (round 18) --------------
// blocks [0, MROWS): LN row; blocks [MROWS, MROWS+768): cvt_t of w_qkv.
// Saves one launch gap; bodies are the verified ln_kernel / cvt_t unchanged.
__global__ __launch_bounds__(256) void ln_cvt_kernel(const float* __restrict__ x,
                                                     const float* __restrict__ gamma,
                                                     const float* __restrict__ beta,
                                                     ushort_t* __restrict__ xnb,
                                                     const float* __restrict__ wq,
                                                     ushort_t* __restrict__ wqkvT)
{
  int bid = blockIdx.x;
  int t = threadIdx.x;
  if (bid < MROWS){
    int row = bid;
    float4 v = ((const float4*)(x + (size_t)row * DIM))[t];
    float s = v.x+v.y+v.z+v.w;
    float ss = v.x*v.x+v.y*v.y+v.z*v.z+v.w*v.w;
    #pragma unroll
    for (int o = 32; o > 0; o >>= 1){ s += __shfl_down(s, o); ss += __shfl_down(ss, o); }
    __shared__ float red[10];
    int wid = t >> 6;
    if ((t & 63) == 0){ red[wid] = s; red[4+wid] = ss; }
    __syncthreads();
    if (t == 0){
      float S0 = red[0]+red[1]+red[2]+red[3];
      float SS = red[4]+red[5]+red[6]+red[7];
      float mu = S0 * (1.f/DIM);
      float var = SS * (1.f/DIM) - mu*mu;
      red[8] = mu; red[9] = rsqrtf(var + 1e-5f);
    }
    __syncthreads();
    float mu = red[8], rstd = red[9];
    float4 g = ((const float4*)gamma)[t];
    float4 b = ((const float4*)beta)[t];
    float f0 = (v.x - mu)*rstd*g.x + b.x;
    float f1 = (v.y - mu)*rstd*g.y + b.y;
    float f2 = (v.z - mu)*rstd*g.z + b.z;
    float f3 = (v.w - mu)*rstd*g.w + b.w;
    *(uint2*)(xnb + (size_t)row*DIM + t*4) = make_uint2(pack2(f0,f1), pack2(f2,f3));
  } else {
    __shared__ float tile[64][65];
    int id = bid - MROWS;                 // 768 blocks: 48 n x 16 k
    int n0 = (id % 48) * 64, k0 = (id / 48) * 64;
    float sc = (n0 < 1024) ? QSCALE : 1.f;
    int c = (t & 15) * 4, r = t >> 4;
    #pragma unroll
    for (int p = 0; p < 4; p++){
      float4 v = *(const float4*)(wq + (size_t)(k0 + r + p*16)*(3*DIM) + n0 + c);
      tile[r+p*16][c]   = v.x; tile[r+p*16][c+1] = v.y;
      tile[r+p*16][c+2] = v.z; tile[r+p*16][c+3] = v.w;
    }
    __syncthreads();
    #pragma unroll
    for (int p = 0; p < 4; p++){
      int nn = r + p*16;
      ushort4 o;
      o.x = f2bf(tile[c+0][nn]*sc); o.y = f2bf(tile[c+1][nn]*sc);
      o.z = f2bf(tile[c+2][nn]*sc); o.w = f2bf(tile[c+3][nn]*sc);
      *(ushort4*)(wqkvT + (size_t)(n0+nn)*DIM + k0 + c) = o;
    }
  }
}

// ------- transpose + fp32->bf16 convert: dst[n][k] = src[k][n] * rowscale ---
__global__ __launch_bounds__(256) void cvt_t(const float* __restrict__ src,
                                             ushort_t* __restrict__ dst,
                                             int K, int N, float qscale)
{
  __shared__ float tile[64][65];
  int k0 = blockIdx.y*64, n0 = blockIdx.x*64;
  float sc = (n0 < 1024) ? qscale : 1.f;
  int t = threadIdx.x;
  int c = (t & 15) * 4, r = t >> 4;
  #pragma unroll
  for (int p = 0; p < 4; p++){
    float4 v = *(const float4*)(src + (size_t)(k0 + r + p*16)*N + n0 + c);
    tile[r+p*16][c]   = v.x; tile[r+p*16][c+1] = v.y;
    tile[r+p*16][c+2] = v.z; tile[r+p*16][c+3] = v.w;
  }
  __syncthreads();
  #pragma unroll
  for (int p = 0; p < 4; p++){
    int nn = r + p*16;
    ushort4 o;
    o.x = f2bf(tile[c+0][nn]*sc); o.y = f2bf(tile[c+1][nn]*sc);
    o.z = f2bf(tile[c+2][nn]*sc); o.w = f2bf(tile[c+3][nn]*sc);
    *(ushort4*)(dst + (size_t)(n0+nn)*K + k0 + c) = o;
  }
}

// ---------------- MFMA GEMM v5: BK=64 + N-strip XCD swizzle -----------------
// Round 18: 1D grid + bijective XCD/N-strip remap. Old dispatch (N fastest)
// re-fetched every B panel for each of 64 M-rounds (B traffic ~6MB x 64 ->
// the 141MB FETCH seen in r4). New map: xcd = bid&7 owns N-panels
// {3*xcd..3*xcd+2} (MODE2, 24=8x3) or {xcd} (MODE0, 8=8x1) for ALL M,
// M-major inside -> B panels L2-resident per XCD (<=768KB), A panels get
// 3x-consecutive reuse. Pure index remap, bijective, zero semantic change.
// BK=64 body verified r17 (-19.5us): half the vmcnt(0)+barrier drains.
template<int MODE, int NCOLS>
__global__ __launch_bounds__(256) void mfma_gemm(
    const ushort_t* __restrict__ A,
    const ushort_t* __restrict__ BT,
    const float* __restrict__ bias,
    void* __restrict__ Cv,
    ushort_t* __restrict__ Vv)
{
  __shared__ __align__(16) unsigned char smem[32768];
  ushort_t* AsL = (ushort_t*)smem;             // [128 rows][64 elems] 16KB
  ushort_t* BsL = (ushort_t*)(smem + 16384);   // [128 rows][64 elems] 16KB

  int t = threadIdx.x;
  int lane = t & 63, w = t >> 6;
  int col = lane & 15, quad = lane >> 4;

  // bijective XCD/N-strip remap
  int bid = blockIdx.x;
  int xcd = bid & 7, idx = bid >> 3;
  int nb, mb;
  if (MODE == 2){ nb = xcd*3 + (idx % 3); mb = idx / 3; }   // 24 N x 64 M
  else          { nb = xcd;               mb = idx;     }   // 8 N x 64 M
  int n0 = nb * 128, m0 = mb * 128;

  f32x4 acc[4][4];
  #pragma unroll
  for (int i = 0; i < 4; i++)
    #pragma unroll
    for (int j = 0; j < 4; j++) acc[i][j] = (f32x4){0.f,0.f,0.f,0.f};

  int mbase = (w & 1)*64 + col;
  int nbase = (w >> 1)*64 + col;

  // ---- staging geometry (BK=64): wave w owns segments {4w..4w+3} ----
  int rloc = lane >> 3, g8 = lane & 7;
  int cA = ((g8 ^ rloc) << 3);                 // logical elem offset (const/lane)
  const ushort_t* gA[4]; const ushort_t* gB[4];
  #pragma unroll
  for (int s = 0; s < 4; s++){
    int row = (4*w + s)*8 + rloc;
    gA[s] = A  + (size_t)(m0 + row)*DIM + cA;
    gB[s] = BT + (size_t)(n0 + row)*DIM + cA;
  }

  // read-side swizzle: per-lane constant; granule (h2*4+quad)^(col&7)
  int pposA = ((quad      ^ (col & 7)) << 3);  // h2 = 0
  int pposB = (((4 + quad) ^ (col & 7)) << 3); // h2 = 1

  for (int k0 = 0; k0 < DIM; k0 += 64){
    __syncthreads();
    #pragma unroll
    for (int s = 0; s < 4; s++){
      GLL16(gA[s] + k0, smem         + (4*w + s)*1024);
      GLL16(gB[s] + k0, smem + 16384 + (4*w + s)*1024);
    }
    __syncthreads();

    bf16x8 af[4], bfr[4];
    #pragma unroll
    for (int i = 0; i < 4; i++){
      af[i]  = *(const bf16x8*)&AsL[(mbase + i*16)*64 + pposA];
      bfr[i] = *(const bf16x8*)&BsL[(nbase + i*16)*64 + pposA];
    }
    #pragma unroll
    for (int mt = 0; mt < 4; mt++)
      #pragma unroll
      for (int nt = 0; nt < 4; nt++)
        acc[mt][nt] = __builtin_amdgcn_mfma_f32_16x16x32_bf16(af[mt], bfr[nt], acc[mt][nt], 0, 0, 0);
    #pragma unroll
    for (int i = 0; i < 4; i++){
      af[i]  = *(const bf16x8*)&AsL[(mbase + i*16)*64 + pposB];
      bfr[i] = *(const bf16x8*)&BsL[(nbase + i*16)*64 + pposB];
    }
    #pragma unroll
    for (int mt = 0; mt < 4; mt++)
      #pragma unroll
      for (int nt = 0; nt < 4; nt++)
        acc[mt][nt] = __builtin_amdgcn_mfma_f32_16x16x32_bf16(af[mt], bfr[nt], acc[mt][nt], 0, 0, 0);
  }

  float bscale = (MODE == 2 && n0 < 1024) ? QSCALE : 1.f;
  float bv[4];
  #pragma unroll
  for (int nt = 0; nt < 4; nt++) bv[nt] = bias[n0 + (w>>1)*64 + nt*16 + col] * bscale;

  if (MODE == 2){
    ushort_t (*Cs)[136] = (ushort_t(*)[136])smem;
    ushort_t* C = (ushort_t*)Cv;
    bool isV = (n0 >= 2*DIM);
    #pragma unroll
    for (int ph = 0; ph < 2; ph++){
      __syncthreads();
      if ((w & 1) == ph){
        #pragma unroll
        for (int mt = 0; mt < 4; mt++)
          #pragma unroll
          for (int nt = 0; nt < 4; nt++)
            #pragma unroll
            for (int r = 0; r < 4; r++)
              Cs[mt*16 + quad*4 + r][(w>>1)*64 + nt*16 + col] = f2bf(acc[mt][nt][r] + bv[nt]);
      }
      __syncthreads();
      if (isV){
        // fused vtrans: Cs rows = 64 consecutive s, cols = 128 dims.
        int mrow = m0 + ph*64;
        int b_ = mrow >> 11, sc = (mrow & (SEQ-1)) >> 6;
        #pragma unroll
        for (int p = 0; p < 4; p++){
          int id2 = p*256 + t;
          int dloc = id2 >> 3;           // 0..127 tile-local dim
          int sg = (id2 & 7) * 8;        // s0 within 64-s chunk
          int n = n0 + dloc;
          int hh = (n >> 6) & 15, dd2 = n & 63;
          int bh2 = b_*NH + hh;
          uint4 uu;
          uu.x = (unsigned)Cs[sg+0][dloc] | ((unsigned)Cs[sg+1][dloc] << 16);
          uu.y = (unsigned)Cs[sg+2][dloc] | ((unsigned)Cs[sg+3][dloc] << 16);
          uu.z = (unsigned)Cs[sg+4][dloc] | ((unsigned)Cs[sg+5][dloc] << 16);
          uu.w = (unsigned)Cs[sg+6][dloc] | ((unsigned)Cs[sg+7][dloc] << 16);
          *(uint4*)&Vv[((size_t)(bh2*32 + sc))*HDIM*64 + dd2*64 + sg] = uu;
        }
      } else {
        #pragma unroll
        for (int p = 0; p < 4; p++){
          int id = p*256 + t;
          int row = id >> 4, cc = id & 15;
          uint4 u = *(const uint4*)&Cs[row][cc*8];
          int m = m0 + ph*64 + row;
          int n = n0 + cc*8;
          int which = n >> 10, hh = (n >> 6) & 15, d = n & 63;
          int b_ = m >> 11, s_ = m & (SEQ-1);
          *(uint4*)&C[((((size_t)which*BN + b_)*NH + hh)*SEQ + s_)*HDIM + d] = u;
        }
      }
    }
  } else {
    float (*Cf)[132] = (float(*)[132])smem;
    float* C = (float*)Cv;
    #pragma unroll
    for (int ph = 0; ph < 4; ph++){
      __syncthreads();
      if ((w & 1) == (ph >> 1)){
        #pragma unroll
        for (int mi = 0; mi < 2; mi++){
          int mt = (ph & 1)*2 + mi;
          #pragma unroll
          for (int nt = 0; nt < 4; nt++)
            #pragma unroll
            for (int r = 0; r < 4; r++)
              Cf[mi*16 + quad*4 + r][(w>>1)*64 + nt*16 + col] = acc[mt][nt][r] + bv[nt];
        }
      }
      __syncthreads();
      #pragma unroll
      for (int p = 0; p < 4; p++){
        int id = p*256 + t;
        int row = id >> 5, cc = id & 31;
        float4 v = *(const float4*)&Cf[row][cc*4];
        int m = m0 + ph*32 + row;
        *(float4*)(C + (size_t)m*NCOLS + n0 + cc*4) = v;
      }
    }
  }
}

// ---------------- MFMA flash attention v13 (verified r16: ~97us) ------------
// v12b double-buffer/1-barrier + T5 setprio. UNCHANGED this round.
__global__ __launch_bounds__(512) void attn_kernel(const ushort_t* __restrict__ qkv,
                                                   const ushort_t* __restrict__ vtp,
                                                   ushort_t* __restrict__ ctx)
{
  __shared__ __align__(16) unsigned char lds[32768];   // K dbuf 16K | V dbuf 16K; Os reuse

  int t = threadIdx.x;
  int lane = t & 63, w = t >> 6;         // w in [0,8)
  int m32 = lane & 31, half = lane >> 5;
  int r7 = m32 & 7;
  int d15 = m32 & 15;                    // dd&15 for both md tiles
  int id = blockIdx.x;                   // 512 blocks: 64 bh x 8 qb
  int bh = (id & 7) | ((id >> 6) << 3);  // XCD-swizzle (L2 locality)
  int qb = (id >> 3) & 7;

  const size_t PL = (size_t)BN * NH * SEQ * HDIM;
  const ushort_t* Qg = qkv + (size_t)bh * (SEQ * HDIM);
  const ushort_t* Kg = Qg + PL;
  const ushort_t* Vt = vtp + (size_t)bh * 32 * (HDIM * 64);
  int qbase = qb*256 + w*32;

  // Q B-frags: B[k=dim][n=q]: lane q=m32, dims c*16 + half*8 + [0,8)
  bf16x8 qf[4];
  #pragma unroll
  for (int c = 0; c < 4; c++)
    qf[c] = *(const bf16x8*)(Qg + (size_t)(qbase + m32)*HDIM + c*16 + half*8);

  bf16x8 ones;
  #pragma unroll
  for (int i = 0; i < 8; i++) ones[i] = (short)0x3F80;

  f32x16 accO[2], accL;
  #pragma unroll
  for (int i = 0; i < 2; i++)
    #pragma unroll
    for (int r = 0; r < 16; r++) accO[i][r] = 0.f;
  #pragma unroll
  for (int r = 0; r < 16; r++) accL[r] = 0.f;

  // staging: 512 threads x (one uint4 K + one uint4 V) per tile.
  int srow = t >> 3, och = t & 7;
  const ushort_t* kp0 = Kg + (size_t)srow*HDIM + och*8;
  const ushort_t* vp0 = Vt + (size_t)srow*64 + och*8;
  int wofsK = srow*64 + ((och ^ (srow & 7)) << 3);
  int wofsV = srow*64 + ((och ^ ((srow >> 1) & 7)) << 3);
  bool vswap = (srow & 1);

  // ---- prologue: stage tile 0 into buf0; prefetch tile 1 ----
  uint4 kr = *(const uint4*)kp0;
  uint4 vr = *(const uint4*)vp0;
  *(uint4*)&((ushort_t*)lds)[wofsK] = kr;
  {
    uint4 vs;
    vs.x = vswap ? vr.z : vr.x;  vs.y = vswap ? vr.w : vr.y;
    vs.z = vswap ? vr.x : vr.z;  vs.w = vswap ? vr.y : vr.w;
    *(uint4*)&((ushort_t*)(lds + 16384))[wofsV] = vs;
  }
  kr = *(const uint4*)(kp0 + (size_t)64*HDIM);      // K[1]
  vr = *(const uint4*)(vp0 + (size_t)HDIM*64);      // V[1]
  __syncthreads();                                  // buf0 visible

  for (int kt = 0; kt < 32; kt++){
    const ushort_t* Kc = (const ushort_t*)(lds + ((kt & 1) << 13));
    const ushort_t* Vc = (const ushort_t*)(lds + 16384 + ((kt & 1) << 13));

    // write NEXT tile into the other buffer (its old readers all finished
    // before the previous barrier), then prefetch tile kt+2.
    if (kt < 31){
      ushort_t* Kn = (ushort_t*)(lds + (((kt + 1) & 1) << 13));
      ushort_t* Vn = (ushort_t*)(lds + 16384 + (((kt + 1) & 1) << 13));
      *(uint4*)&Kn[wofsK] = kr;
      uint4 vs;
      vs.x = vswap ? vr.z : vr.x;  vs.y = vswap ? vr.w : vr.y;
      vs.z = vswap ? vr.x : vr.z;  vs.w = vswap ? vr.y : vr.w;
      *(uint4*)&Vn[wofsV] = vs;
      int nk = (kt + 2 <= 31) ? kt + 2 : 31;        // clamped (harmless reload)
      kr = *(const uint4*)(kp0 + (size_t)nk*64*HDIM);
      vr = *(const uint4*)(vp0 + (size_t)nk*HDIM*64);
    }

    // ---- per key-tile of 32: S^T = K Q^T, p = exp2(s), pack (RAW order) ----
    bf16x8 pb[4];
    #pragma unroll
    for (int mt = 0; mt < 2; mt++){
      f32x16 z;
      #pragma unroll
      for (int r = 0; r < 16; r++) z[r] = 0.f;
      int rowb = (mt*32 + m32) * 64;       // row = key; row&7 == r7
      __builtin_amdgcn_s_setprio(1);
      #pragma unroll
      for (int c = 0; c < 4; c++){
        bf16x8 af = *(const bf16x8*)&Kc[rowb + (((2*c + half) ^ r7) << 3)];
        z = __builtin_amdgcn_mfma_f32_32x32x16_bf16(af, qf[c], z, 0, 0, 0);
      }
      __builtin_amdgcn_s_setprio(0);
      unsigned u[8];
      #pragma unroll
      for (int i = 0; i < 8; i++){
        float p0 = __builtin_amdgcn_exp2f(z[2*i]);
        float p1 = __builtin_amdgcn_exp2f(z[2*i+1]);
        bf16v2 hh; hh.x = (__bf16)p0; hh.y = (__bf16)p1;
        u[i] = __builtin_bit_cast(unsigned, hh);
      }
      #pragma unroll
      for (int cc = 0; cc < 2; cc++){
        union { uint4 q; bf16x8 b; } cvt;
        cvt.q = make_uint4(u[4*cc+0], u[4*cc+1], u[4*cc+2], u[4*cc+3]);
        pb[mt*2 + cc] = cvt.b;   // raw order: slot (h,e) holds key 8(e>>2)+4h+(e&3)
      }
    }

    // ---- PV + l-sum interleaved; V reads via 8B-granule swizzle ----
    __builtin_amdgcn_s_setprio(1);
    #pragma unroll
    for (int kc = 0; kc < 4; kc++){
      accL = __builtin_amdgcn_mfma_f32_32x32x16_bf16(ones, pb[kc], accL, 0, 0, 0);
      #pragma unroll
      for (int md = 0; md < 2; md++){
        int rowb = (md*32 + m32) * 64;
        union { bf16x8 v8; uint2 u2[2]; } vv;
        vv.u2[0] = *(const uint2*)&Vc[rowb + (((4*kc     + half) ^ d15) << 2)];
        vv.u2[1] = *(const uint2*)&Vc[rowb + (((4*kc + 2 + half) ^ d15) << 2)];
        accO[md] = __builtin_amdgcn_mfma_f32_32x32x16_bf16(vv.v8, pb[kc], accO[md], 0, 0, 0);
      }
    }
    __builtin_amdgcn_s_setprio(0);

    if (kt < 31) __syncthreads();        // next buffer's writes visible
  }

  // ---- epilogue: l = accL[0]; Os reuses staging LDS after full barrier ----
  __syncthreads();                       // all waves done with K/V buffers
  float inv = 1.f / accL[0];

  // wave-private 4KB slice; [32 q][64 d] with 16B-granule swizzle p=j^(row&7)
  ushort_t* Osm = (ushort_t*)(lds + w*4096);
  #pragma unroll
  for (int md = 0; md < 2; md++)
    #pragma unroll
    for (int g = 0; g < 4; g++){
      int j16 = g + 4*md;                          // 16B granule of d0=8g+32md
      int p = j16 ^ r7;                            // row = m32
      unsigned lo = pack2(accO[md][4*g+0]*inv, accO[md][4*g+1]*inv);
      unsigned hi = pack2(accO[md][4*g+2]*inv, accO[md][4*g+3]*inv);
      *(uint2*)&Osm[m32*64 + p*8 + half*4] = make_uint2(lo, hi);
    }

  int b_ = bh >> 4, h_ = bh & 15;
  #pragma unroll
  for (int k = 0; k < 4; k++){
    int row = k*8 + (lane >> 3);
    int p = (lane & 7) ^ (row & 7);
    uint4 u = *(const uint4*)&Osm[row*64 + p*8];
    *(uint4*)(ctx + ((size_t)(b_*SEQ + qb*256 + w*32 + row))*DIM + h_*HDIM + (lane & 7)*8) = u;
  }
}

extern "C" void kernel_launch(void* const* d_in, const int* in_sizes, int n_in,
                              void* d_out, int out_size, void* d_ws, size_t ws_size,
                              hipStream_t stream)
{
  const float* x      = (const float*)d_in[0];
  const float* gamma  = (const float*)d_in[1];
  const float* beta   = (const float*)d_in[2];
  const float* w_qkv  = (const float*)d_in[3];
  const float* b_qkv  = (const float*)d_in[4];
  const float* w_proj = (const float*)d_in[5];
  const float* b_proj = (const float*)d_in[6];

  // ws (64 MB), layout (vtrans fused into QKV GEMM epilogue, r15-verified):
  //   wqkvT  0..6MB     (written ln_cvt; read QKV GEMM; dead after)
  //   qkv Q  16..32MB   (written QKV GEMM; read attn; dead after attn)
  //   qkv K  32..48MB   (written QKV GEMM; read attn)
  //   vt     48..64MB   (written DIRECTLY by QKV GEMM V-epilogue; read attn)
  //   ctx    0..16MB    (written attn — wqkvT dead; read proj GEMM)
  //   wprojT 16..18MB   (written cvt_t after attn — Q plane dead; read proj)
  // xnb (16MB bf16 LN output) in the FIRST HALF OF d_out (32MB f32): dead
  // after QKV GEMM; proj GEMM overwrites all of d_out. Every region is
  // written before read within each launch -> deterministic across replays.
  char* ws = (char*)d_ws;
  ushort_t* wqkvT  = (ushort_t*)ws;
  ushort_t* qkv    = (ushort_t*)(ws + 16u*1024*1024);
  ushort_t* vt     = (ushort_t*)(ws + 48u*1024*1024);
  ushort_t* ctx    = (ushort_t*)ws;
  ushort_t* wprojT = (ushort_t*)(ws + 16u*1024*1024);
  ushort_t* xnb    = (ushort_t*)d_out;

  ln_cvt_kernel<<<MROWS + 768, 256, 0, stream>>>(x, gamma, beta, xnb, w_qkv, wqkvT);
  mfma_gemm<2, 3*DIM><<<1536, 256, 0, stream>>>(xnb, wqkvT, b_qkv, qkv, vt);
  attn_kernel<<<BN*NH*(SEQ/256), 512, 0, stream>>>(qkv, vt, ctx);
  cvt_t<<<dim3(DIM/64, DIM/64), 256, 0, stream>>>(w_proj, wprojT, DIM, DIM, 1.f);
  mfma_gemm<0, DIM><<<512, 256, 0, stream>>>(ctx, wprojT, b_proj, d_out, nullptr);
}

// Round 19
// 276.874 us; speedup vs baseline: 1.0271x; 1.0271x over previous
//
#include <hip/hip_runtime.h>

typedef unsigned short ushort_t;
typedef __attribute__((ext_vector_type(8))) short bf16x8;
typedef __attribute__((ext_vector_type(4))) float f32x4;
typedef __attribute__((ext_vector_type(16))) float f32x16;
typedef __attribute__((ext_vector_type(2))) __bf16 bf16v2;

#define BN 4
#define SEQ 2048
#define DIM 1024
#define NH 16
#define HDIM 64
#define MROWS (BN*SEQ)   // 8192
#define QSCALE 0.18033688011112042f   // 0.125 * log2(e): folded into Q so p = exp2(s)

__device__ __forceinline__ float bf2f(ushort_t s){ return __uint_as_float(((unsigned)s) << 16); }
__device__ __forceinline__ ushort_t f2bf(float f){
  unsigned u = __float_as_uint(f);
  u += 0x7fffu + ((u >> 16) & 1u);   // round-to-nearest-even
  return (ushort_t)(u >> 16);
}
__device__ __forceinline__ unsigned pack2(float a, float b){
  return (unsigned)f2bf(a) | ((unsigned)f2bf(b) << 16);
}

// async global->LDS copy, 16B per lane; LDS dest = wave-uniform base + lane*16
#define GLL16(gp, lp) __builtin_amdgcn_global_load_lds( \
    (const __attribute__((address_space(1))) void*)(gp), \
    (__attribute__((address_space(3))) void*)(lp), 16, 0, 0)

// ------- fused LN + w_qkv transpose in ONE dispatch (kept from r18) ---------
// blocks [0, MROWS): LN row; blocks [MROWS, MROWS+768): cvt_t of w_qkv.
// Saves one launch gap; bodies are the verified ln_kernel / cvt_t unchanged.
__global__ __launch_bounds__(256) void ln_cvt_kernel(const float* __restrict__ x,
                                                     const float* __restrict__ gamma,
                                                     const float* __restrict__ beta,
                                                     ushort_t* __restrict__ xnb,
                                                     const float* __restrict__ wq,
                                                     ushort_t* __restrict__ wqkvT)
{
  int bid = blockIdx.x;
  int t = threadIdx.x;
  if (bid < MROWS){
    int row = bid;
    float4 v = ((const float4*)(x + (size_t)row * DIM))[t];
    float s = v.x+v.y+v.z+v.w;
    float ss = v.x*v.x+v.y*v.y+v.z*v.z+v.w*v.w;
    #pragma unroll
    for (int o = 32; o > 0; o >>= 1){ s += __shfl_down(s, o); ss += __shfl_down(ss, o); }
    __shared__ float red[10];
    int wid = t >> 6;
    if ((t & 63) == 0){ red[wid] = s; red[4+wid] = ss; }
    __syncthreads();
    if (t == 0){
      float S0 = red[0]+red[1]+red[2]+red[3];
      float SS = red[4]+red[5]+red[6]+red[7];
      float mu = S0 * (1.f/DIM);
      float var = SS * (1.f/DIM) - mu*mu;
      red[8] = mu; red[9] = rsqrtf(var + 1e-5f);
    }
    __syncthreads();
    float mu = red[8], rstd = red[9];
    float4 g = ((const float4*)gamma)[t];
    float4 b = ((const float4*)beta)[t];
    float f0 = (v.x - mu)*rstd*g.x + b.x;
    float f1 = (v.y - mu)*rstd*g.y + b.y;
    float f2 = (v.z - mu)*rstd*g.z + b.z;
    float f3 = (v.w - mu)*rstd*g.w + b.w;
    *(uint2*)(xnb + (size_t)row*DIM + t*4) = make_uint2(pack2(f0,f1), pack2(f2,f3));
  } else {
    __shared__ float tile[64][65];
    int id = bid - MROWS;                 // 768 blocks: 48 n x 16 k
    int n0 = (id % 48) * 64, k0 = (id / 48) * 64;
    float sc = (n0 < 1024) ? QSCALE : 1.f;
    int c = (t & 15) * 4, r = t >> 4;
    #pragma unroll
    for (int p = 0; p < 4; p++){
      float4 v = *(const float4*)(wq + (size_t)(k0 + r + p*16)*(3*DIM) + n0 + c);
      tile[r+p*16][c]   = v.x; tile[r+p*16][c+1] = v.y;
      tile[r+p*16][c+2] = v.z; tile[r+p*16][c+3] = v.w;
    }
    __syncthreads();
    #pragma unroll
    for (int p = 0; p < 4; p++){
      int nn = r + p*16;
      ushort4 o;
      o.x = f2bf(tile[c+0][nn]*sc); o.y = f2bf(tile[c+1][nn]*sc);
      o.z = f2bf(tile[c+2][nn]*sc); o.w = f2bf(tile[c+3][nn]*sc);
      *(ushort4*)(wqkvT + (size_t)(n0+nn)*DIM + k0 + c) = o;
    }
  }
}

// ------- transpose + fp32->bf16 convert: dst[n][k] = src[k][n] * rowscale ---
__global__ __launch_bounds__(256) void cvt_t(const float* __restrict__ src,
                                             ushort_t* __restrict__ dst,
                                             int K, int N, float qscale)
{
  __shared__ float tile[64][65];
  int k0 = blockIdx.y*64, n0 = blockIdx.x*64;
  float sc = (n0 < 1024) ? qscale : 1.f;
  int t = threadIdx.x;
  int c = (t & 15) * 4, r = t >> 4;
  #pragma unroll
  for (int p = 0; p < 4; p++){
    float4 v = *(const float4*)(src + (size_t)(k0 + r + p*16)*N + n0 + c);
    tile[r+p*16][c]   = v.x; tile[r+p*16][c+1] = v.y;
    tile[r+p*16][c+2] = v.z; tile[r+p*16][c+3] = v.w;
  }
  __syncthreads();
  #pragma unroll
  for (int p = 0; p < 4; p++){
    int nn = r + p*16;
    ushort4 o;
    o.x = f2bf(tile[c+0][nn]*sc); o.y = f2bf(tile[c+1][nn]*sc);
    o.z = f2bf(tile[c+2][nn]*sc); o.w = f2bf(tile[c+3][nn]*sc);
    *(ushort4*)(dst + (size_t)(n0+nn)*K + k0 + c) = o;
  }
}

// ---------------- MFMA GEMM v5b: BK=64, N-fastest 2D grid (r17-verified) ----
// Round 19: REVERT of r18's N-strip XCD swizzle (regressed -5us: M-major
// order per XCD made the A working set 21x256KB ~= 5.4MB > 4MB per-XCD L2 —
// I fixed B-residency but broke A-residency; N-fastest keeps A resident and
// lets L3 absorb B). BK=64 body is r17's verified -19.5us win: half the
// vmcnt(0)+barrier drains. MODE 0: f32 row-major C (proj). MODE 2: bf16
// qkv-layout C + Q-scaled bias + fused V-transpose epilogue (r15-verified).
template<int MODE, int NCOLS>
__global__ __launch_bounds__(256) void mfma_gemm(
    const ushort_t* __restrict__ A,
    const ushort_t* __restrict__ BT,
    const float* __restrict__ bias,
    void* __restrict__ Cv,
    ushort_t* __restrict__ Vv)
{
  __shared__ __align__(16) unsigned char smem[32768];
  ushort_t* AsL = (ushort_t*)smem;             // [128 rows][64 elems] 16KB
  ushort_t* BsL = (ushort_t*)(smem + 16384);   // [128 rows][64 elems] 16KB

  int t = threadIdx.x;
  int lane = t & 63, w = t >> 6;
  int col = lane & 15, quad = lane >> 4;
  int n0 = blockIdx.x * 128, m0 = blockIdx.y * 128;

  f32x4 acc[4][4];
  #pragma unroll
  for (int i = 0; i < 4; i++)
    #pragma unroll
    for (int j = 0; j < 4; j++) acc[i][j] = (f32x4){0.f,0.f,0.f,0.f};

  int mbase = (w & 1)*64 + col;
  int nbase = (w >> 1)*64 + col;

  // ---- staging geometry (BK=64): wave w owns segments {4w..4w+3} ----
  // segment s = 8 rows (1KB); lane i -> row s*8 + (i>>3), physical granule
  // i&7, which receives LOGICAL granule (i&7)^(row&7) = (i&7)^(i>>3).
  int rloc = lane >> 3, g8 = lane & 7;
  int cA = ((g8 ^ rloc) << 3);                 // logical elem offset (const/lane)
  const ushort_t* gA[4]; const ushort_t* gB[4];
  #pragma unroll
  for (int s = 0; s < 4; s++){
    int row = (4*w + s)*8 + rloc;
    gA[s] = A  + (size_t)(m0 + row)*DIM + cA;
    gB[s] = BT + (size_t)(n0 + row)*DIM + cA;
  }

  // read-side swizzle: per-lane constant; granule (h2*4+quad)^(col&7)
  int pposA = ((quad      ^ (col & 7)) << 3);  // h2 = 0
  int pposB = (((4 + quad) ^ (col & 7)) << 3); // h2 = 1

  for (int k0 = 0; k0 < DIM; k0 += 64){
    __syncthreads();
    #pragma unroll
    for (int s = 0; s < 4; s++){
      GLL16(gA[s] + k0, smem         + (4*w + s)*1024);
      GLL16(gB[s] + k0, smem + 16384 + (4*w + s)*1024);
    }
    __syncthreads();

    // h2 = 0 (k0..k0+31), then h2 = 1 (k0+32..k0+63) — same order as two
    // BK=32 iterations -> bitwise-identical accumulation.
    bf16x8 af[4], bfr[4];
    #pragma unroll
    for (int i = 0; i < 4; i++){
      af[i]  = *(const bf16x8*)&AsL[(mbase + i*16)*64 + pposA];
      bfr[i] = *(const bf16x8*)&BsL[(nbase + i*16)*64 + pposA];
    }
    #pragma unroll
    for (int mt = 0; mt < 4; mt++)
      #pragma unroll
      for (int nt = 0; nt < 4; nt++)
        acc[mt][nt] = __builtin_amdgcn_mfma_f32_16x16x32_bf16(af[mt], bfr[nt], acc[mt][nt], 0, 0, 0);
    #pragma unroll
    for (int i = 0; i < 4; i++){
      af[i]  = *(const bf16x8*)&AsL[(mbase + i*16)*64 + pposB];
      bfr[i] = *(const bf16x8*)&BsL[(nbase + i*16)*64 + pposB];
    }
    #pragma unroll
    for (int mt = 0; mt < 4; mt++)
      #pragma unroll
      for (int nt = 0; nt < 4; nt++)
        acc[mt][nt] = __builtin_amdgcn_mfma_f32_16x16x32_bf16(af[mt], bfr[nt], acc[mt][nt], 0, 0, 0);
  }

  float bscale = (MODE == 2 && n0 < 1024) ? QSCALE : 1.f;
  float bv[4];
  #pragma unroll
  for (int nt = 0; nt < 4; nt++) bv[nt] = bias[n0 + (w>>1)*64 + nt*16 + col] * bscale;

  if (MODE == 2){
    ushort_t (*Cs)[136] = (ushort_t(*)[136])smem;
    ushort_t* C = (ushort_t*)Cv;
    bool isV = (n0 >= 2*DIM);
    #pragma unroll
    for (int ph = 0; ph < 2; ph++){
      __syncthreads();
      if ((w & 1) == ph){
        #pragma unroll
        for (int mt = 0; mt < 4; mt++)
          #pragma unroll
          for (int nt = 0; nt < 4; nt++)
            #pragma unroll
            for (int r = 0; r < 4; r++)
              Cs[mt*16 + quad*4 + r][(w>>1)*64 + nt*16 + col] = f2bf(acc[mt][nt][r] + bv[nt]);
      }
      __syncthreads();
      if (isV){
        // fused vtrans: Cs rows = 64 consecutive s, cols = 128 dims.
        int mrow = m0 + ph*64;
        int b_ = mrow >> 11, sc = (mrow & (SEQ-1)) >> 6;
        #pragma unroll
        for (int p = 0; p < 4; p++){
          int id2 = p*256 + t;
          int dloc = id2 >> 3;           // 0..127 tile-local dim
          int sg = (id2 & 7) * 8;        // s0 within 64-s chunk
          int n = n0 + dloc;
          int hh = (n >> 6) & 15, dd2 = n & 63;
          int bh2 = b_*NH + hh;
          uint4 uu;
          uu.x = (unsigned)Cs[sg+0][dloc] | ((unsigned)Cs[sg+1][dloc] << 16);
          uu.y = (unsigned)Cs[sg+2][dloc] | ((unsigned)Cs[sg+3][dloc] << 16);
          uu.z = (unsigned)Cs[sg+4][dloc] | ((unsigned)Cs[sg+5][dloc] << 16);
          uu.w = (unsigned)Cs[sg+6][dloc] | ((unsigned)Cs[sg+7][dloc] << 16);
          *(uint4*)&Vv[((size_t)(bh2*32 + sc))*HDIM*64 + dd2*64 + sg] = uu;
        }
      } else {
        #pragma unroll
        for (int p = 0; p < 4; p++){
          int id = p*256 + t;
          int row = id >> 4, cc = id & 15;
          uint4 u = *(const uint4*)&Cs[row][cc*8];
          int m = m0 + ph*64 + row;
          int n = n0 + cc*8;
          int which = n >> 10, hh = (n >> 6) & 15, d = n & 63;
          int b_ = m >> 11, s_ = m & (SEQ-1);
          *(uint4*)&C[((((size_t)which*BN + b_)*NH + hh)*SEQ + s_)*HDIM + d] = u;
        }
      }
    }
  } else {
    float (*Cf)[132] = (float(*)[132])smem;
    float* C = (float*)Cv;
    #pragma unroll
    for (int ph = 0; ph < 4; ph++){
      __syncthreads();
      if ((w & 1) == (ph >> 1)){
        #pragma unroll
        for (int mi = 0; mi < 2; mi++){
          int mt = (ph & 1)*2 + mi;
          #pragma unroll
          for (int nt = 0; nt < 4; nt++)
            #pragma unroll
            for (int r = 0; r < 4; r++)
              Cf[mi*16 + quad*4 + r][(w>>1)*64 + nt*16 + col] = acc[mt][nt][r] + bv[nt];
        }
      }
      __syncthreads();
      #pragma unroll
      for (int p = 0; p < 4; p++){
        int id = p*256 + t;
        int row = id >> 5, cc = id & 31;
        float4 v = *(const float4*)&Cf[row][cc*4];
        int m = m0 + ph*32 + row;
        *(float4*)(C + (size_t)m*NCOLS + n0 + cc*4) = v;
      }
    }
  }
}

// ---------------- MFMA flash attention v13 (verified r16/r18: ~95-97us) -----
// v12b double-buffer/1-barrier + T5 setprio. UNCHANGED this round.
__global__ __launch_bounds__(512) void attn_kernel(const ushort_t* __restrict__ qkv,
                                                   const ushort_t* __restrict__ vtp,
                                                   ushort_t* __restrict__ ctx)
{
  __shared__ __align__(16) unsigned char lds[32768];   // K dbuf 16K | V dbuf 16K; Os reuse

  int t = threadIdx.x;
  int lane = t & 63, w = t >> 6;         // w in [0,8)
  int m32 = lane & 31, half = lane >> 5;
  int r7 = m32 & 7;
  int d15 = m32 & 15;                    // dd&15 for both md tiles
  int id = blockIdx.x;                   // 512 blocks: 64 bh x 8 qb
  int bh = (id & 7) | ((id >> 6) << 3);  // XCD-swizzle (L2 locality)
  int qb = (id >> 3) & 7;

  const size_t PL = (size_t)BN * NH * SEQ * HDIM;
  const ushort_t* Qg = qkv + (size_t)bh * (SEQ * HDIM);
  const ushort_t* Kg = Qg + PL;
  const ushort_t* Vt = vtp + (size_t)bh * 32 * (HDIM * 64);
  int qbase = qb*256 + w*32;

  // Q B-frags: B[k=dim][n=q]: lane q=m32, dims c*16 + half*8 + [0,8)
  bf16x8 qf[4];
  #pragma unroll
  for (int c = 0; c < 4; c++)
    qf[c] = *(const bf16x8*)(Qg + (size_t)(qbase + m32)*HDIM + c*16 + half*8);

  bf16x8 ones;
  #pragma unroll
  for (int i = 0; i < 8; i++) ones[i] = (short)0x3F80;

  f32x16 accO[2], accL;
  #pragma unroll
  for (int i = 0; i < 2; i++)
    #pragma unroll
    for (int r = 0; r < 16; r++) accO[i][r] = 0.f;
  #pragma unroll
  for (int r = 0; r < 16; r++) accL[r] = 0.f;

  // staging: 512 threads x (one uint4 K + one uint4 V) per tile.
  int srow = t >> 3, och = t & 7;
  const ushort_t* kp0 = Kg + (size_t)srow*HDIM + och*8;
  const ushort_t* vp0 = Vt + (size_t)srow*64 + och*8;
  int wofsK = srow*64 + ((och ^ (srow & 7)) << 3);
  int wofsV = srow*64 + ((och ^ ((srow >> 1) & 7)) << 3);
  bool vswap = (srow & 1);

  // ---- prologue: stage tile 0 into buf0; prefetch tile 1 ----
  uint4 kr = *(const uint4*)kp0;
  uint4 vr = *(const uint4*)vp0;
  *(uint4*)&((ushort_t*)lds)[wofsK] = kr;
  {
    uint4 vs;
    vs.x = vswap ? vr.z : vr.x;  vs.y = vswap ? vr.w : vr.y;
    vs.z = vswap ? vr.x : vr.z;  vs.w = vswap ? vr.y : vr.w;
    *(uint4*)&((ushort_t*)(lds + 16384))[wofsV] = vs;
  }
  kr = *(const uint4*)(kp0 + (size_t)64*HDIM);      // K[1]
  vr = *(const uint4*)(vp0 + (size_t)HDIM*64);      // V[1]
  __syncthreads();                                  // buf0 visible

  for (int kt = 0; kt < 32; kt++){
    const ushort_t* Kc = (const ushort_t*)(lds + ((kt & 1) << 13));
    const ushort_t* Vc = (const ushort_t*)(lds + 16384 + ((kt & 1) << 13));

    // write NEXT tile into the other buffer (its old readers all finished
    // before the previous barrier), then prefetch tile kt+2.
    if (kt < 31){
      ushort_t* Kn = (ushort_t*)(lds + (((kt + 1) & 1) << 13));
      ushort_t* Vn = (ushort_t*)(lds + 16384 + (((kt + 1) & 1) << 13));
      *(uint4*)&Kn[wofsK] = kr;
      uint4 vs;
      vs.x = vswap ? vr.z : vr.x;  vs.y = vswap ? vr.w : vr.y;
      vs.z = vswap ? vr.x : vr.z;  vs.w = vswap ? vr.y : vr.w;
      *(uint4*)&Vn[wofsV] = vs;
      int nk = (kt + 2 <= 31) ? kt + 2 : 31;        // clamped (harmless reload)
      kr = *(const uint4*)(kp0 + (size_t)nk*64*HDIM);
      vr = *(const uint4*)(vp0 + (size_t)nk*HDIM*64);
    }

    // ---- per key-tile of 32: S^T = K Q^T, p = exp2(s), pack (RAW order) ----
    bf16x8 pb[4];
    #pragma unroll
    for (int mt = 0; mt < 2; mt++){
      f32x16 z;
      #pragma unroll
      for (int r = 0; r < 16; r++) z[r] = 0.f;
      int rowb = (mt*32 + m32) * 64;       // row = key; row&7 == r7
      __builtin_amdgcn_s_setprio(1);
      #pragma unroll
      for (int c = 0; c < 4; c++){
        bf16x8 af = *(const bf16x8*)&Kc[rowb + (((2*c + half) ^ r7) << 3)];
        z = __builtin_amdgcn_mfma_f32_32x32x16_bf16(af, qf[c], z, 0, 0, 0);
      }
      __builtin_amdgcn_s_setprio(0);
      unsigned u[8];
      #pragma unroll
      for (int i = 0; i < 8; i++){
        float p0 = __builtin_amdgcn_exp2f(z[2*i]);
        float p1 = __builtin_amdgcn_exp2f(z[2*i+1]);
        bf16v2 hh; hh.x = (__bf16)p0; hh.y = (__bf16)p1;
        u[i] = __builtin_bit_cast(unsigned, hh);
      }
      #pragma unroll
      for (int cc = 0; cc < 2; cc++){
        union { uint4 q; bf16x8 b; } cvt;
        cvt.q = make_uint4(u[4*cc+0], u[4*cc+1], u[4*cc+2], u[4*cc+3]);
        pb[mt*2 + cc] = cvt.b;   // raw order: slot (h,e) holds key 8(e>>2)+4h+(e&3)
      }
    }

    // ---- PV + l-sum interleaved; V reads via 8B-granule swizzle ----
    __builtin_amdgcn_s_setprio(1);
    #pragma unroll
    for (int kc = 0; kc < 4; kc++){
      accL = __builtin_amdgcn_mfma_f32_32x32x16_bf16(ones, pb[kc], accL, 0, 0, 0);
      #pragma unroll
      for (int md = 0; md < 2; md++){
        int rowb = (md*32 + m32) * 64;
        union { bf16x8 v8; uint2 u2[2]; } vv;
        vv.u2[0] = *(const uint2*)&Vc[rowb + (((4*kc     + half) ^ d15) << 2)];
        vv.u2[1] = *(const uint2*)&Vc[rowb + (((4*kc + 2 + half) ^ d15) << 2)];
        accO[md] = __builtin_amdgcn_mfma_f32_32x32x16_bf16(vv.v8, pb[kc], accO[md], 0, 0, 0);
      }
    }
    __builtin_amdgcn_s_setprio(0);

    if (kt < 31) __syncthreads();        // next buffer's writes visible
  }

  // ---- epilogue: l = accL[0]; Os reuses staging LDS after full barrier ----
  __syncthreads();                       // all waves done with K/V buffers
  float inv = 1.f / accL[0];

  // wave-private 4KB slice; [32 q][64 d] with 16B-granule swizzle p=j^(row&7)
  ushort_t* Osm = (ushort_t*)(lds + w*4096);
  #pragma unroll
  for (int md = 0; md < 2; md++)
    #pragma unroll
    for (int g = 0; g < 4; g++){
      int j16 = g + 4*md;                          // 16B granule of d0=8g+32md
      int p = j16 ^ r7;                            // row = m32
      unsigned lo = pack2(accO[md][4*g+0]*inv, accO[md][4*g+1]*inv);
      unsigned hi = pack2(accO[md][4*g+2]*inv, accO[md][4*g+3]*inv);
      *(uint2*)&Osm[m32*64 + p*8 + half*4] = make_uint2(lo, hi);
    }

  int b_ = bh >> 4, h_ = bh & 15;
  #pragma unroll
  for (int k = 0; k < 4; k++){
    int row = k*8 + (lane >> 3);
    int p = (lane & 7) ^ (row & 7);
    uint4 u = *(const uint4*)&Osm[row*64 + p*8];
    *(uint4*)(ctx + ((size_t)(b_*SEQ + qb*256 + w*32 + row))*DIM + h_*HDIM + (lane & 7)*8) = u;
  }
}

extern "C" void kernel_launch(void* const* d_in, const int* in_sizes, int n_in,
                              void* d_out, int out_size, void* d_ws, size_t ws_size,
                              hipStream_t stream)
{
  const float* x      = (const float*)d_in[0];
  const float* gamma  = (const float*)d_in[1];
  const float* beta   = (const float*)d_in[2];
  const float* w_qkv  = (const float*)d_in[3];
  const float* b_qkv  = (const float*)d_in[4];
  const float* w_proj = (const float*)d_in[5];
  const float* b_proj = (const float*)d_in[6];

  // ws (64 MB), layout (vtrans fused into QKV GEMM epilogue, r15-verified):
  //   wqkvT  0..6MB     (written ln_cvt; read QKV GEMM; dead after)
  //   qkv Q  16..32MB   (written QKV GEMM; read attn; dead after attn)
  //   qkv K  32..48MB   (written QKV GEMM; read attn)
  //   vt     48..64MB   (written DIRECTLY by QKV GEMM V-epilogue; read attn)
  //   ctx    0..16MB    (written attn — wqkvT dead; read proj GEMM)
  //   wprojT 16..18MB   (written cvt_t after attn — Q plane dead; read proj)
  // xnb (16MB bf16 LN output) in the FIRST HALF OF d_out (32MB f32): dead
  // after QKV GEMM; proj GEMM overwrites all of d_out. Every region is
  // written before read within each launch -> deterministic across replays.
  char* ws = (char*)d_ws;
  ushort_t* wqkvT  = (ushort_t*)ws;
  ushort_t* qkv    = (ushort_t*)(ws + 16u*1024*1024);
  ushort_t* vt     = (ushort_t*)(ws + 48u*1024*1024);
  ushort_t* ctx    = (ushort_t*)ws;
  ushort_t* wprojT = (ushort_t*)(ws + 16u*1024*1024);
  ushort_t* xnb    = (ushort_t*)d_out;

  ln_cvt_kernel<<<MROWS + 768, 256, 0, stream>>>(x, gamma, beta, xnb, w_qkv, wqkvT);
  mfma_gemm<2, 3*DIM><<<dim3(3*DIM/128, MROWS/128), 256, 0, stream>>>(
      xnb, wqkvT, b_qkv, qkv, vt);
  attn_kernel<<<BN*NH*(SEQ/256), 512, 0, stream>>>(qkv, vt, ctx);
  cvt_t<<<dim3(DIM/64, DIM/64), 256, 0, stream>>>(w_proj, wprojT, DIM, DIM, 1.f);
  mfma_gemm<0, DIM><<<dim3(DIM/128, MROWS/128), 256, 0, stream>>>(
      ctx, wprojT, b_proj, d_out, nullptr);
}